// Round 1
// baseline (151.720 us; speedup 1.0000x reference)
//
#include <hip/hip_runtime.h>
#include <math.h>

#define B 4
#define S 4096
#define DIN 1024
#define DOUT 64
#define BS (B * S)

typedef __bf16 bf16;
typedef __bf16 bf16x4 __attribute__((ext_vector_type(4)));
typedef __bf16 bf16x8 __attribute__((ext_vector_type(8)));
typedef float f32x4 __attribute__((ext_vector_type(4)));

// log2(e)/64: folds the 1/sqrt(S)=1/64 score scale and exp->exp2 into Q.
#define QSCALE 0.022542110013890053f

// Workspace layout (bytes), ~23.5 MB of the 256 MiB ws:
//   Qs : 0      [BS][64] bf16 (pre-scaled by log2e/64), row-major
//   KF : 2 MB   QK^T B-fragment order: [tile 256][nt 4][c 2][lane 64][j 8] bf16
//   VF : 4 MB   PV  B-fragment order: [tile 256][c 2][ntd 4][lane 64][j 8] bf16
//   WP : 6 MB   [12][32][64][8] bf16 (projection B-fragment order)
//   OP : 7 MB   [4096 slots][32 q][64 d] bf16  unnormalized eighth-partial O
//   LP : 23 MB  [4096 slots][32 q] f32         eighth-partial row sums
#define QS_OFF 0
#define KF_OFF (2u * 1024 * 1024)
#define VF_OFF (4u * 1024 * 1024)
#define WP_OFF (6u * 1024 * 1024)
#define OP_OFF (7u * 1024 * 1024)
#define LP_OFF (23u * 1024 * 1024)

// ---------------------------------------------------------------------------
// W repack, COALESCED reads, scattered fire-and-forget bf16 stores.
// wp[((nt*32+kc)*64 + lane)*8 + j] = W[k][n],
//   k = kc*32 + (lane>>4)*8 + j, n = nt*16 + (lane&15).
// ---------------------------------------------------------------------------
__global__ __launch_bounds__(256) void wpack_kernel(
    const float* __restrict__ Wq, const float* __restrict__ Wk,
    const float* __restrict__ Wv, bf16* __restrict__ wp) {
  const int t = blockIdx.x * 256 + threadIdx.x;  // [0, 196608)
  const int m = t >> 16;                         // 0=Q 1=K 2=V
  const int r = t & 65535;                       // k*64 + n64
  const int k = r >> 6;
  const int n64 = r & 63;
  const float* W = (m == 0) ? Wq : (m == 1) ? Wk : Wv;
  const float v = W[r];                          // coalesced
  const int n = m * 64 + n64;
  const int nt = n >> 4;
  const int lane = ((k >> 3) & 3) * 16 + (n & 15);
  const int idx = ((nt * 32 + (k >> 5)) * 64 + lane) * 8 + (k & 7);
  wp[idx] = (bf16)v;
}

// ---------------------------------------------------------------------------
// QKV projection, MFMA 16x16x32 bf16, 8-WAVE BLOCKS + T14 PIPELINED STAGING.
// Round-8 counters: MfmaUtil 5%, VALUBusy 7%, HBM 13%, occupancy 18% ->
// latency-bound (x is HBM-cold: the 262MB ws poison thrashes L3 each iter).
// Fix: (a) 512-thread blocks over the same 32 rows -> 16 waves/CU (2x TLP);
// wave wid owns strip wid>>2 x nt-group wid&3 (3 MFMA/kc, acc[3]).
// (b) T14 issue-early: phase-1 x loads are issued right after the phase-0
// barrier (sched_barrier-pinned) so their HBM latency hides under phase-0's
// wp-load + MFMA stream; the LDS write lands after the next barrier.
// Epilogue unchanged: Q row-major, K/V directly in attention B-frag order.
// ---------------------------------------------------------------------------
__global__ __launch_bounds__(512, 4) void qkv_mfma_kernel(
    const float* __restrict__ x, const float* __restrict__ bq,
    const float* __restrict__ bk, const float* __restrict__ bv,
    const bf16* __restrict__ wp, bf16* __restrict__ Qs,
    bf16* __restrict__ KF, bf16* __restrict__ VF) {
  __shared__ __align__(16) bf16 xt[32][520];  // 33280 B; stride 520: 2-way banks

  const int tid = threadIdx.x;
  const int wid = tid >> 6;      // 0..7
  const int lane = tid & 63;
  const int l15 = lane & 15;
  const int quad = lane >> 4;
  const int st = wid >> 2;       // row strip (16 rows) this wave owns
  const int w4 = wid & 3;        // nt group: nt = w4*3 + j
  const int blk = blockIdx.x;    // rows [blk*32, blk*32+32)

  const bf16x8* wp8 = (const bf16x8*)wp;

  f32x4 acc[3];
#pragma unroll
  for (int j = 0; j < 3; ++j) acc[j] = (f32x4)(0.f);

  float4 v[8];

  // ---- stage phase 0: 8 float4/thread, back-to-back ----
#pragma unroll
  for (int i = 0; i < 8; ++i) {
    const int ch = i * 512 + tid;  // [0,4096): row*128 + col4
    v[i] = *(const float4*)(x + (size_t)(blk * 32 + (ch >> 7)) * DIN +
                            (ch & 127) * 4);
  }
#pragma unroll
  for (int i = 0; i < 8; ++i) {
    const int ch = i * 512 + tid;
    bf16x4 c4;
    c4[0] = (bf16)v[i].x; c4[1] = (bf16)v[i].y;
    c4[2] = (bf16)v[i].z; c4[3] = (bf16)v[i].w;
    *(bf16x4*)&xt[ch >> 7][(ch & 127) * 4] = c4;
  }
  __syncthreads();

  // ---- T14: issue phase-1 loads NOW; they retire during phase-0 compute ----
#pragma unroll
  for (int i = 0; i < 8; ++i) {
    const int ch = i * 512 + tid;
    v[i] = *(const float4*)(x + (size_t)(blk * 32 + (ch >> 7)) * DIN + 512 +
                            (ch & 127) * 4);
  }
  __builtin_amdgcn_sched_barrier(0);  // pin the issues above the compute

  // ---- compute phase 0: 16 kc x (3 wp loads + 1 ds_read + 3 MFMA) ----
#pragma unroll 4
  for (int kc = 0; kc < 16; ++kc) {
    bf16x8 bfr[3];
#pragma unroll
    for (int j = 0; j < 3; ++j)
      bfr[j] = wp8[((w4 * 3 + j) * 32 + kc) * 64 + lane];
    const bf16x8 a = *(const bf16x8*)&xt[st * 16 + l15][quad * 8 + kc * 32];
#pragma unroll
    for (int j = 0; j < 3; ++j)
      acc[j] = __builtin_amdgcn_mfma_f32_16x16x32_bf16(a, bfr[j], acc[j], 0, 0, 0);
  }
  __syncthreads();

  // ---- write phase 1 to LDS (loads already long in flight) ----
#pragma unroll
  for (int i = 0; i < 8; ++i) {
    const int ch = i * 512 + tid;
    bf16x4 c4;
    c4[0] = (bf16)v[i].x; c4[1] = (bf16)v[i].y;
    c4[2] = (bf16)v[i].z; c4[3] = (bf16)v[i].w;
    *(bf16x4*)&xt[ch >> 7][(ch & 127) * 4] = c4;
  }
  __syncthreads();

  // ---- compute phase 1 ----
#pragma unroll 4
  for (int kc = 0; kc < 16; ++kc) {
    bf16x8 bfr[3];
#pragma unroll
    for (int j = 0; j < 3; ++j)
      bfr[j] = wp8[((w4 * 3 + j) * 32 + 16 + kc) * 64 + lane];
    const bf16x8 a = *(const bf16x8*)&xt[st * 16 + l15][quad * 8 + kc * 32];
#pragma unroll
    for (int j = 0; j < 3; ++j)
      acc[j] = __builtin_amdgcn_mfma_f32_16x16x32_bf16(a, bfr[j], acc[j], 0, 0, 0);
  }

  // ---- epilogue: per-wave (strip, nt) slices, fragment-order K/V stores ----
#pragma unroll
  for (int j = 0; j < 3; ++j) {
    const int nt = w4 * 3 + j;
    const int sel = nt >> 2;             // 0=Q 1=K 2=V (wave-uniform per j)
    const int c = (nt & 3) * 16 + l15;   // output column (d)
    const float bias = ((sel == 0) ? bq : (sel == 1) ? bk : bv)[c];
    const int row0 = blk * 32 + st * 16 + quad * 4;  // 4 consecutive rows
    if (sel == 0) {
#pragma unroll
      for (int r = 0; r < 4; ++r)
        Qs[(size_t)(row0 + r) * DOUT + c] =
            (bf16)((acc[j][r] + bias) * QSCALE);
    } else if (sel == 1) {
      // KF[((t*4+nt)*2+ck)*64 + ((c>>3)&3)*16 + (key&15)]*8 + (c&7)
      const size_t kb =
          ((size_t)(((row0 >> 6) * 4 + ((row0 >> 4) & 3)) * 2 + (c >> 5)) * 64 +
           ((c >> 3) & 3) * 16 + quad * 4) * 8 + (c & 7);
#pragma unroll
      for (int r = 0; r < 4; ++r)
        KF[kb + r * 8] = (bf16)(acc[j][r] + bias);
    } else {
      // VF[((t*2+cv)*4+ntd)*64 + (c&15) + 16*((key>>3)&3)]*8 + (key&7)
      const size_t vb =
          ((size_t)(((row0 >> 6) * 2 + ((row0 >> 5) & 1)) * 4 + (c >> 4)) * 64 +
           (c & 15) + 16 * ((row0 >> 3) & 3)) * 8 + (row0 & 7);
      bf16x4 vv;
#pragma unroll
      for (int r = 0; r < 4; ++r) vv[r] = (bf16)(acc[j][r] + bias);
      *(bf16x4*)(VF + vb) = vv;
    }
  }
}

// ---------------------------------------------------------------------------
// Flash attention, MFMA 16x16x32 bf16, BARRIER-FREE fragment-direct.
// K/V pre-packed in B-fragment order -> each wave's fragment loads are
// contiguous 1 KB wave-loads from L2 (no LDS staging, no __syncthreads).
// Block = (batch, 32-row strip s32, key-half); 4 waves = quarters of the
// half (key-EIGHTHS).  Each wave: 32 q-rows x its key tiles, fully
// independent; only the per-wave P C->A LDS round-trip remains (lgkmcnt-
// ordered within the wave).  Logits pre-scaled by log2e/64 -> exp2, no
// online max.  Eighth-partials (O bf16, l f32) to ws; combine finishes.
// ---------------------------------------------------------------------------
__global__ __launch_bounds__(256) void attn_mfma_kernel(
    const bf16* __restrict__ Qs, const bf16* __restrict__ KFp,
    const bf16* __restrict__ VFp, bf16* __restrict__ Oh,
    float* __restrict__ lh) {
  __shared__ __align__(16) bf16 pw[4][32][72];  // 18432 B, per-wave regions

  const int tid = threadIdx.x;
  const int wid = tid >> 6;
  const int lane = tid & 63;
  const int l15 = lane & 15;
  const int quad = lane >> 4;
  const int b = blockIdx.x & 3;                // XCD affinity by batch
  const int half = (blockIdx.x >> 2) & 1;
  const int s32 = 127 - (blockIdx.x >> 3);     // LPT: longest first
  const int ntiles = (s32 >> 1) + 1;
  const int e = half * 4 + wid;                // eighth 0..7
  const int t0 = (e * ntiles) >> 3;
  const int t1 = ((e + 1) * ntiles) >> 3;

  const bf16x8* KF8 = (const bf16x8*)KFp;
  const bf16x8* VF8 = (const bf16x8*)VFp;
  const int tb0 = b * 64;

  // Q A-frags, 2 strips x 2 k-chunks
  const bf16* Qb = Qs + ((size_t)b * S + s32 * 32) * DOUT;
  bf16x8 qf[2][2];
#pragma unroll
  for (int st = 0; st < 2; ++st)
#pragma unroll
    for (int k = 0; k < 2; ++k)
      qf[st][k] =
          *(const bf16x8*)(Qb + (st * 16 + l15) * DOUT + k * 32 + quad * 8);

  f32x4 o[2][4];
#pragma unroll
  for (int st = 0; st < 2; ++st)
#pragma unroll
    for (int i = 0; i < 4; ++i) o[st][i] = (f32x4)(0.f);
  f32x4 lsum[2] = {(f32x4)(0.f), (f32x4)(0.f)};

  for (int t = t0; t < t1; ++t) {
    const int tb = tb0 + t;
    // fragment loads: 16 contiguous 1KB wave-loads (all issued before use)
    bf16x8 kf[8], vf[8];
#pragma unroll
    for (int nt = 0; nt < 4; ++nt)
#pragma unroll
      for (int c = 0; c < 2; ++c)
        kf[nt * 2 + c] = KF8[(size_t)((tb * 4 + nt) * 2 + c) * 64 + lane];
#pragma unroll
    for (int c = 0; c < 2; ++c)
#pragma unroll
      for (int ntd = 0; ntd < 4; ++ntd)
        vf[c * 4 + ntd] = VF8[(size_t)((tb * 2 + c) * 4 + ntd) * 64 + lane];

    // S = Q K^T, both strips
    f32x4 s[2][4];
#pragma unroll
    for (int st = 0; st < 2; ++st)
#pragma unroll
      for (int nt = 0; nt < 4; ++nt) {
        s[st][nt] = __builtin_amdgcn_mfma_f32_16x16x32_bf16(
            qf[st][0], kf[nt * 2 + 0], (f32x4)(0.f), 0, 0, 0);
        s[st][nt] = __builtin_amdgcn_mfma_f32_16x16x32_bf16(
            qf[st][1], kf[nt * 2 + 1], s[st][nt], 0, 0, 0);
      }

    // p = exp2(s), causal mask only on the diagonal (last) tile
    if (t == ntiles - 1) {
#pragma unroll
      for (int st = 0; st < 2; ++st)
#pragma unroll
        for (int nt = 0; nt < 4; ++nt) {
          const int key = t * 64 + nt * 16 + l15;
#pragma unroll
          for (int r = 0; r < 4; ++r) {
            const int qrow = s32 * 32 + st * 16 + quad * 4 + r;
            const float p = (key <= qrow) ? exp2f(fminf(s[st][nt][r], 44.f)) : 0.f;
            lsum[st][r] += p;
            pw[wid][st * 16 + quad * 4 + r][nt * 16 + l15] = (bf16)p;
          }
        }
    } else {
#pragma unroll
      for (int st = 0; st < 2; ++st)
#pragma unroll
        for (int nt = 0; nt < 4; ++nt)
#pragma unroll
          for (int r = 0; r < 4; ++r) {
            const float p = exp2f(fminf(s[st][nt][r], 44.f));
            lsum[st][r] += p;
            pw[wid][st * 16 + quad * 4 + r][nt * 16 + l15] = (bf16)p;
          }
    }

    // P C->A layout round-trip (same-wave LDS; lgkmcnt orders it), then PV
#pragma unroll
    for (int st = 0; st < 2; ++st) {
      const bf16x8 pf0 = *(const bf16x8*)&pw[wid][st * 16 + l15][quad * 8];
      const bf16x8 pf1 = *(const bf16x8*)&pw[wid][st * 16 + l15][32 + quad * 8];
#pragma unroll
      for (int ntd = 0; ntd < 4; ++ntd) {
        o[st][ntd] = __builtin_amdgcn_mfma_f32_16x16x32_bf16(
            pf0, vf[0 * 4 + ntd], o[st][ntd], 0, 0, 0);
        o[st][ntd] = __builtin_amdgcn_mfma_f32_16x16x32_bf16(
            pf1, vf[1 * 4 + ntd], o[st][ntd], 0, 0, 0);
      }
    }
  }

  // row sums across the 16 lanes of each quad
#pragma unroll
  for (int m = 1; m < 16; m <<= 1)
#pragma unroll
    for (int st = 0; st < 2; ++st)
#pragma unroll
      for (int r = 0; r < 4; ++r) lsum[st][r] += __shfl_xor(lsum[st][r], m, 64);

  const int slot = (b * 128 + s32) * 8 + e;
  if (l15 == 0) {
#pragma unroll
    for (int st = 0; st < 2; ++st)
#pragma unroll
      for (int r = 0; r < 4; ++r)
        lh[slot * 32 + st * 16 + quad * 4 + r] = lsum[st][r];
  }
#pragma unroll
  for (int st = 0; st < 2; ++st)
#pragma unroll
    for (int ntd = 0; ntd < 4; ++ntd)
#pragma unroll
      for (int r = 0; r < 4; ++r)
        Oh[(size_t)slot * 2048 + (st * 16 + quad * 4 + r) * 64 + ntd * 16 + l15] =
            (bf16)o[st][ntd][r];
}

// ---------------------------------------------------------------------------
// Sum the 8 eighth-partials and normalize.  262144 f32x4 -> grid 1024x256.
// ---------------------------------------------------------------------------
__global__ __launch_bounds__(256) void combine_kernel(
    const bf16* __restrict__ Oh, const float* __restrict__ lh,
    float* __restrict__ out) {
  const int gid = blockIdx.x * 256 + threadIdx.x;  // [0, 262144)
  const int token = gid >> 4;                      // 0..16383
  const int d4 = (gid & 15) * 4;
  const int b = token >> 12;
  const int s = token & 4095;
  const int s32 = s >> 5;
  const int qq = s & 31;
  const int slot0 = (b * 128 + s32) * 8;
  f32x4 acc = (f32x4)(0.f);
  float l = 0.f;
#pragma unroll
  for (int q = 0; q < 8; ++q) {
    const bf16x4 ov =
        *(const bf16x4*)(Oh + (size_t)(slot0 + q) * 2048 + qq * 64 + d4);
#pragma unroll
    for (int i = 0; i < 4; ++i) acc[i] += (float)ov[i];
    l += lh[(slot0 + q) * 32 + qq];
  }
  ((f32x4*)out)[gid] = acc * (1.f / l);
}

// ---------------------------------------------------------------------------
extern "C" void kernel_launch(void* const* d_in, const int* in_sizes, int n_in,
                              void* d_out, int out_size, void* d_ws,
                              size_t ws_size, hipStream_t stream) {
  const float* x  = (const float*)d_in[0];
  const float* Wq = (const float*)d_in[1];
  const float* bq = (const float*)d_in[2];
  const float* Wk = (const float*)d_in[3];
  const float* bk = (const float*)d_in[4];
  const float* Wv = (const float*)d_in[5];
  const float* bv = (const float*)d_in[6];
  float* out = (float*)d_out;

  char* ws = (char*)d_ws;
  bf16* Qs = (bf16*)(ws + QS_OFF);
  bf16* KF = (bf16*)(ws + KF_OFF);
  bf16* VF = (bf16*)(ws + VF_OFF);
  bf16* wp = (bf16*)(ws + WP_OFF);
  bf16* Oh = (bf16*)(ws + OP_OFF);
  float* lh = (float*)(ws + LP_OFF);

  wpack_kernel<<<768, 256, 0, stream>>>(Wq, Wk, Wv, wp);
  qkv_mfma_kernel<<<512, 512, 0, stream>>>(x, bq, bk, bv, wp, Qs, KF, VF);
  attn_mfma_kernel<<<1024, 256, 0, stream>>>(Qs, KF, VF, Oh, lh);
  combine_kernel<<<1024, 256, 0, stream>>>(Oh, lh, out);
}

// Round 2
// 147.351 us; speedup vs baseline: 1.0297x; 1.0297x over previous
//
#include <hip/hip_runtime.h>
#include <math.h>

#define B 4
#define S 4096
#define DIN 1024
#define DOUT 64
#define BS (B * S)

typedef __bf16 bf16;
typedef __bf16 bf16x4 __attribute__((ext_vector_type(4)));
typedef __bf16 bf16x8 __attribute__((ext_vector_type(8)));
typedef float f32x4 __attribute__((ext_vector_type(4)));

// log2(e)/64: folds the 1/sqrt(S)=1/64 score scale and exp->exp2 into Q.
#define QSCALE 0.022542110013890053f

// Workspace layout (bytes), ~23.5 MB of the 256 MiB ws:
//   Qs : 0      [BS][64] bf16 (pre-scaled by log2e/64), row-major
//   KF : 2 MB   QK^T B-fragment order: [tile 256][nt 4][c 2][lane 64][j 8] bf16
//   VF : 4 MB   PV  B-fragment order: [tile 256][c 2][ntd 4][lane 64][j 8] bf16
//   WP : 6 MB   [12][32][64][8] bf16 (projection B-fragment order)
//   OP : 7 MB   [4096 slots][32 q][64 d] bf16  unnormalized eighth-partial O
//   LP : 23 MB  [4096 slots][32 q] f32         eighth-partial row sums
#define QS_OFF 0
#define KF_OFF (2u * 1024 * 1024)
#define VF_OFF (4u * 1024 * 1024)
#define WP_OFF (6u * 1024 * 1024)
#define OP_OFF (7u * 1024 * 1024)
#define LP_OFF (23u * 1024 * 1024)

// ---------------------------------------------------------------------------
// W repack, COALESCED reads, scattered fire-and-forget bf16 stores.
// wp[((nt*32+kc)*64 + lane)*8 + j] = W[k][n],
//   k = kc*32 + (lane>>4)*8 + j, n = nt*16 + (lane&15).
// ---------------------------------------------------------------------------
__global__ __launch_bounds__(256) void wpack_kernel(
    const float* __restrict__ Wq, const float* __restrict__ Wk,
    const float* __restrict__ Wv, bf16* __restrict__ wp) {
  const int t = blockIdx.x * 256 + threadIdx.x;  // [0, 196608)
  const int m = t >> 16;                         // 0=Q 1=K 2=V
  const int r = t & 65535;                       // k*64 + n64
  const int k = r >> 6;
  const int n64 = r & 63;
  const float* W = (m == 0) ? Wq : (m == 1) ? Wk : Wv;
  const float v = W[r];                          // coalesced
  const int n = m * 64 + n64;
  const int nt = n >> 4;
  const int lane = ((k >> 3) & 3) * 16 + (n & 15);
  const int idx = ((nt * 32 + (k >> 5)) * 64 + lane) * 8 + (k & 7);
  wp[idx] = (bf16)v;
}

// ---------------------------------------------------------------------------
// QKV projection, MFMA 16x16x32 bf16, 64-ROW BLOCKS for wp AMORTIZATION.
// Rounds 0/1 A/B: doubling waves/CU (18->38% occ) left dur at ~43us and the
// aggregate stream rate pinned at ~10.6 TB/s -> per-CU request-path cap, not
// latency.  Dominant bytes: every 32-row block re-read the FULL 768KB wp
// (512 blocks -> 400 MB for a 786KB operand).  Fix: 64-row blocks (grid 256)
// halve wp traffic to 200MB, and each wave now applies its 3 wp fragments to
// ALL 4 row strips: per kc = 3 wp loads + 4 ds_reads -> 12 MFMA (1:4 ratio,
// was 1:1).  LDS 66.5KB -> 2 blocks/CU.
// Epilogue unchanged: Q row-major, K/V directly in attention B-frag order.
// ---------------------------------------------------------------------------
__global__ __launch_bounds__(256) void qkv_mfma_kernel(
    const float* __restrict__ x, const float* __restrict__ bq,
    const float* __restrict__ bk, const float* __restrict__ bv,
    const bf16* __restrict__ wp, bf16* __restrict__ Qs,
    bf16* __restrict__ KF, bf16* __restrict__ VF) {
  __shared__ __align__(16) bf16 xt[64][520];  // 66560 B; stride 520: 2-way banks

  const int tid = threadIdx.x;
  const int wid = tid >> 6;      // 0..3 -> nt group
  const int lane = tid & 63;
  const int l15 = lane & 15;
  const int quad = lane >> 4;
  const int blk = blockIdx.x;    // rows [blk*64, blk*64+64)

  const bf16x8* wp8 = (const bf16x8*)wp;

  f32x4 acc[3][4];               // [j][strip]
#pragma unroll
  for (int j = 0; j < 3; ++j)
#pragma unroll
    for (int s = 0; s < 4; ++s) acc[j][s] = (f32x4)(0.f);

  for (int ph = 0; ph < 2; ++ph) {
    if (ph) __syncthreads();  // compute of phase 0 done before overwrite
    // ---- stage 64 rows x 512 cols: 4 bursts of 8 float4/thread ----
#pragma unroll
    for (int bst = 0; bst < 4; ++bst) {
      float4 v[8];
#pragma unroll
      for (int i = 0; i < 8; ++i) {
        const int ch = (bst * 8 + i) * 256 + tid;  // [0,8192): row*128+col4
        v[i] = *(const float4*)(x + (size_t)(blk * 64 + (ch >> 7)) * DIN +
                                ph * 512 + (ch & 127) * 4);
      }
#pragma unroll
      for (int i = 0; i < 8; ++i) {
        const int ch = (bst * 8 + i) * 256 + tid;
        bf16x4 c4;
        c4[0] = (bf16)v[i].x; c4[1] = (bf16)v[i].y;
        c4[2] = (bf16)v[i].z; c4[3] = (bf16)v[i].w;
        *(bf16x4*)&xt[ch >> 7][(ch & 127) * 4] = c4;
      }
    }
    __syncthreads();

    // ---- compute: 16 kc x (3 wp loads + 4 ds_reads + 12 MFMA) ----
#pragma unroll 4
    for (int kc = 0; kc < 16; ++kc) {
      bf16x8 bfr[3];
#pragma unroll
      for (int j = 0; j < 3; ++j)
        bfr[j] = wp8[((wid * 3 + j) * 32 + ph * 16 + kc) * 64 + lane];
      bf16x8 a[4];
#pragma unroll
      for (int s = 0; s < 4; ++s)
        a[s] = *(const bf16x8*)&xt[s * 16 + l15][quad * 8 + kc * 32];
#pragma unroll
      for (int j = 0; j < 3; ++j)
#pragma unroll
        for (int s = 0; s < 4; ++s)
          acc[j][s] = __builtin_amdgcn_mfma_f32_16x16x32_bf16(
              a[s], bfr[j], acc[j][s], 0, 0, 0);
    }
  }

  // ---- epilogue: per-wave nt slices x 4 strips, fragment-order stores ----
#pragma unroll
  for (int j = 0; j < 3; ++j) {
    const int nt = wid * 3 + j;
    const int sel = nt >> 2;             // 0=Q 1=K 2=V (wave-uniform per j)
    const int c = (nt & 3) * 16 + l15;   // output column (d)
    const float bias = ((sel == 0) ? bq : (sel == 1) ? bk : bv)[c];
#pragma unroll
    for (int s = 0; s < 4; ++s) {
      const int row0 = blk * 64 + s * 16 + quad * 4;  // 4 consecutive rows
      if (sel == 0) {
#pragma unroll
        for (int r = 0; r < 4; ++r)
          Qs[(size_t)(row0 + r) * DOUT + c] =
              (bf16)((acc[j][s][r] + bias) * QSCALE);
      } else if (sel == 1) {
        // KF[((t*4+nt)*2+ck)*64 + ((c>>3)&3)*16 + (key&15)]*8 + (c&7)
        const size_t kb =
            ((size_t)(((row0 >> 6) * 4 + ((row0 >> 4) & 3)) * 2 + (c >> 5)) * 64 +
             ((c >> 3) & 3) * 16 + quad * 4) * 8 + (c & 7);
#pragma unroll
        for (int r = 0; r < 4; ++r)
          KF[kb + r * 8] = (bf16)(acc[j][s][r] + bias);
      } else {
        // VF[((t*2+cv)*4+ntd)*64 + (c&15) + 16*((key>>3)&3)]*8 + (key&7)
        const size_t vb =
            ((size_t)(((row0 >> 6) * 2 + ((row0 >> 5) & 1)) * 4 + (c >> 4)) * 64 +
             (c & 15) + 16 * ((row0 >> 3) & 3)) * 8 + (row0 & 7);
        bf16x4 vv;
#pragma unroll
        for (int r = 0; r < 4; ++r) vv[r] = (bf16)(acc[j][s][r] + bias);
        *(bf16x4*)(VF + vb) = vv;
      }
    }
  }
}

// ---------------------------------------------------------------------------
// Flash attention, MFMA 16x16x32 bf16, BARRIER-FREE fragment-direct.
// K/V pre-packed in B-fragment order -> each wave's fragment loads are
// contiguous 1 KB wave-loads from L2 (no LDS staging, no __syncthreads).
// Block = (batch, 32-row strip s32, key-half); 4 waves = quarters of the
// half (key-EIGHTHS).  Each wave: 32 q-rows x its key tiles, fully
// independent; only the per-wave P C->A LDS round-trip remains (lgkmcnt-
// ordered within the wave).  Logits pre-scaled by log2e/64 -> exp2, no
// online max.  Eighth-partials (O bf16, l f32) to ws; combine finishes.
// ---------------------------------------------------------------------------
__global__ __launch_bounds__(256) void attn_mfma_kernel(
    const bf16* __restrict__ Qs, const bf16* __restrict__ KFp,
    const bf16* __restrict__ VFp, bf16* __restrict__ Oh,
    float* __restrict__ lh) {
  __shared__ __align__(16) bf16 pw[4][32][72];  // 18432 B, per-wave regions

  const int tid = threadIdx.x;
  const int wid = tid >> 6;
  const int lane = tid & 63;
  const int l15 = lane & 15;
  const int quad = lane >> 4;
  const int b = blockIdx.x & 3;                // XCD affinity by batch
  const int half = (blockIdx.x >> 2) & 1;
  const int s32 = 127 - (blockIdx.x >> 3);     // LPT: longest first
  const int ntiles = (s32 >> 1) + 1;
  const int e = half * 4 + wid;                // eighth 0..7
  const int t0 = (e * ntiles) >> 3;
  const int t1 = ((e + 1) * ntiles) >> 3;

  const bf16x8* KF8 = (const bf16x8*)KFp;
  const bf16x8* VF8 = (const bf16x8*)VFp;
  const int tb0 = b * 64;

  // Q A-frags, 2 strips x 2 k-chunks
  const bf16* Qb = Qs + ((size_t)b * S + s32 * 32) * DOUT;
  bf16x8 qf[2][2];
#pragma unroll
  for (int st = 0; st < 2; ++st)
#pragma unroll
    for (int k = 0; k < 2; ++k)
      qf[st][k] =
          *(const bf16x8*)(Qb + (st * 16 + l15) * DOUT + k * 32 + quad * 8);

  f32x4 o[2][4];
#pragma unroll
  for (int st = 0; st < 2; ++st)
#pragma unroll
    for (int i = 0; i < 4; ++i) o[st][i] = (f32x4)(0.f);
  f32x4 lsum[2] = {(f32x4)(0.f), (f32x4)(0.f)};

  for (int t = t0; t < t1; ++t) {
    const int tb = tb0 + t;
    // fragment loads: 16 contiguous 1KB wave-loads (all issued before use)
    bf16x8 kf[8], vf[8];
#pragma unroll
    for (int nt = 0; nt < 4; ++nt)
#pragma unroll
      for (int c = 0; c < 2; ++c)
        kf[nt * 2 + c] = KF8[(size_t)((tb * 4 + nt) * 2 + c) * 64 + lane];
#pragma unroll
    for (int c = 0; c < 2; ++c)
#pragma unroll
      for (int ntd = 0; ntd < 4; ++ntd)
        vf[c * 4 + ntd] = VF8[(size_t)((tb * 2 + c) * 4 + ntd) * 64 + lane];

    // S = Q K^T, both strips
    f32x4 s[2][4];
#pragma unroll
    for (int st = 0; st < 2; ++st)
#pragma unroll
      for (int nt = 0; nt < 4; ++nt) {
        s[st][nt] = __builtin_amdgcn_mfma_f32_16x16x32_bf16(
            qf[st][0], kf[nt * 2 + 0], (f32x4)(0.f), 0, 0, 0);
        s[st][nt] = __builtin_amdgcn_mfma_f32_16x16x32_bf16(
            qf[st][1], kf[nt * 2 + 1], s[st][nt], 0, 0, 0);
      }

    // p = exp2(s), causal mask only on the diagonal (last) tile
    if (t == ntiles - 1) {
#pragma unroll
      for (int st = 0; st < 2; ++st)
#pragma unroll
        for (int nt = 0; nt < 4; ++nt) {
          const int key = t * 64 + nt * 16 + l15;
#pragma unroll
          for (int r = 0; r < 4; ++r) {
            const int qrow = s32 * 32 + st * 16 + quad * 4 + r;
            const float p = (key <= qrow) ? exp2f(fminf(s[st][nt][r], 44.f)) : 0.f;
            lsum[st][r] += p;
            pw[wid][st * 16 + quad * 4 + r][nt * 16 + l15] = (bf16)p;
          }
        }
    } else {
#pragma unroll
      for (int st = 0; st < 2; ++st)
#pragma unroll
        for (int nt = 0; nt < 4; ++nt)
#pragma unroll
          for (int r = 0; r < 4; ++r) {
            const float p = exp2f(fminf(s[st][nt][r], 44.f));
            lsum[st][r] += p;
            pw[wid][st * 16 + quad * 4 + r][nt * 16 + l15] = (bf16)p;
          }
    }

    // P C->A layout round-trip (same-wave LDS; lgkmcnt orders it), then PV
#pragma unroll
    for (int st = 0; st < 2; ++st) {
      const bf16x8 pf0 = *(const bf16x8*)&pw[wid][st * 16 + l15][quad * 8];
      const bf16x8 pf1 = *(const bf16x8*)&pw[wid][st * 16 + l15][32 + quad * 8];
#pragma unroll
      for (int ntd = 0; ntd < 4; ++ntd) {
        o[st][ntd] = __builtin_amdgcn_mfma_f32_16x16x32_bf16(
            pf0, vf[0 * 4 + ntd], o[st][ntd], 0, 0, 0);
        o[st][ntd] = __builtin_amdgcn_mfma_f32_16x16x32_bf16(
            pf1, vf[1 * 4 + ntd], o[st][ntd], 0, 0, 0);
      }
    }
  }

  // row sums across the 16 lanes of each quad
#pragma unroll
  for (int m = 1; m < 16; m <<= 1)
#pragma unroll
    for (int st = 0; st < 2; ++st)
#pragma unroll
      for (int r = 0; r < 4; ++r) lsum[st][r] += __shfl_xor(lsum[st][r], m, 64);

  const int slot = (b * 128 + s32) * 8 + e;
  if (l15 == 0) {
#pragma unroll
    for (int st = 0; st < 2; ++st)
#pragma unroll
      for (int r = 0; r < 4; ++r)
        lh[slot * 32 + st * 16 + quad * 4 + r] = lsum[st][r];
  }
#pragma unroll
  for (int st = 0; st < 2; ++st)
#pragma unroll
    for (int ntd = 0; ntd < 4; ++ntd)
#pragma unroll
      for (int r = 0; r < 4; ++r)
        Oh[(size_t)slot * 2048 + (st * 16 + quad * 4 + r) * 64 + ntd * 16 + l15] =
            (bf16)o[st][ntd][r];
}

// ---------------------------------------------------------------------------
// Sum the 8 eighth-partials and normalize.  262144 f32x4 -> grid 1024x256.
// ---------------------------------------------------------------------------
__global__ __launch_bounds__(256) void combine_kernel(
    const bf16* __restrict__ Oh, const float* __restrict__ lh,
    float* __restrict__ out) {
  const int gid = blockIdx.x * 256 + threadIdx.x;  // [0, 262144)
  const int token = gid >> 4;                      // 0..16383
  const int d4 = (gid & 15) * 4;
  const int b = token >> 12;
  const int s = token & 4095;
  const int s32 = s >> 5;
  const int qq = s & 31;
  const int slot0 = (b * 128 + s32) * 8;
  f32x4 acc = (f32x4)(0.f);
  float l = 0.f;
#pragma unroll
  for (int q = 0; q < 8; ++q) {
    const bf16x4 ov =
        *(const bf16x4*)(Oh + (size_t)(slot0 + q) * 2048 + qq * 64 + d4);
#pragma unroll
    for (int i = 0; i < 4; ++i) acc[i] += (float)ov[i];
    l += lh[(slot0 + q) * 32 + qq];
  }
  ((f32x4*)out)[gid] = acc * (1.f / l);
}

// ---------------------------------------------------------------------------
extern "C" void kernel_launch(void* const* d_in, const int* in_sizes, int n_in,
                              void* d_out, int out_size, void* d_ws,
                              size_t ws_size, hipStream_t stream) {
  const float* x  = (const float*)d_in[0];
  const float* Wq = (const float*)d_in[1];
  const float* bq = (const float*)d_in[2];
  const float* bk = (const float*)d_in[4];
  const float* Wk = (const float*)d_in[3];
  const float* Wv = (const float*)d_in[5];
  const float* bv = (const float*)d_in[6];
  float* out = (float*)d_out;

  char* ws = (char*)d_ws;
  bf16* Qs = (bf16*)(ws + QS_OFF);
  bf16* KF = (bf16*)(ws + KF_OFF);
  bf16* VF = (bf16*)(ws + VF_OFF);
  bf16* wp = (bf16*)(ws + WP_OFF);
  bf16* Oh = (bf16*)(ws + OP_OFF);
  float* lh = (float*)(ws + LP_OFF);

  wpack_kernel<<<768, 256, 0, stream>>>(Wq, Wk, Wv, wp);
  qkv_mfma_kernel<<<256, 256, 0, stream>>>(x, bq, bk, bv, wp, Qs, KF, VF);
  attn_mfma_kernel<<<1024, 256, 0, stream>>>(Qs, KF, VF, Oh, lh);
  combine_kernel<<<1024, 256, 0, stream>>>(Oh, lh, out);
}